// Round 10
// baseline (325.102 us; speedup 1.0000x reference)
//
#include <hip/hip_runtime.h>

#define TT 168
#define HH 64
#define DD 7
#define NS 32      // samples per block: 2 N=16 MFMA sample-tiles
#define BB 8192
#define CH 8       // timesteps per staged x chunk
#define NTH 1024   // 16 waves: eng = wv>>3 (L0/L1), gh = (wv>>2)&1 (gate pair), ug = wv&3

typedef float f32x4 __attribute__((ext_vector_type(4)));
typedef _Float16 f16x8 __attribute__((ext_vector_type(8)));

#define MFMA16F(A, B, C) __builtin_amdgcn_mfma_f32_16x16x32_f16((A), (B), (C), 0, 0, 0)

// weights split hi+lo fp16 (covers fp32 mantissa), data single fp16
#define TERM2(G, Wh, Wl, D)   \
    G = MFMA16F(Wh, (D), G);  \
    G = MFMA16F(Wl, (D), G);

// weight split: hi = RTNE fp16, lo = residual
__device__ __forceinline__ void wsplit8(f32x4 a, f32x4 b, f16x8& hi, f16x8& lo) {
#pragma unroll
    for (int e = 0; e < 4; ++e) {
        const _Float16 h = (_Float16)a[e];
        hi[e] = h; lo[e] = (_Float16)(a[e] - (float)h);
    }
#pragma unroll
    for (int e = 0; e < 4; ++e) {
        const _Float16 h = (_Float16)b[e];
        hi[4 + e] = h; lo[4 + e] = (_Float16)(b[e] - (float)h);
    }
}
__device__ __forceinline__ f16x8 pack8(f32x4 a, f32x4 b) {
    f16x8 r;
#pragma unroll
    for (int e = 0; e < 4; ++e) { r[e] = (_Float16)a[e]; r[4 + e] = (_Float16)b[e]; }
    return r;
}

// fast activations: v_exp_f32 + v_rcp_f32, saturation-safe
__device__ __forceinline__ float sigf(float v) {
    return __builtin_amdgcn_rcpf(1.0f + __builtin_amdgcn_exp2f(v * -1.44269504f));
}
__device__ __forceinline__ float thf(float v) {
    return fmaf(-2.0f, __builtin_amdgcn_rcpf(__builtin_amdgcn_exp2f(v * 2.88539008f) + 1.0f), 1.0f);
}

// cell update (4 units, 1 sample) + fp16 writeback of h to LDS
__device__ __forceinline__ void cell_update(const f32x4& gi, const f32x4& gf,
                                            const f32x4& gg, const f32x4& go,
                                            f32x4& cst, _Float16* dst) {
    f32x4 hv;
#pragma unroll
    for (int r = 0; r < 4; ++r) {
        const float iv = sigf(gi[r]), fv = sigf(gf[r]);
        const float gv = thf(gg[r]),  ov = sigf(go[r]);
        cst[r] = fv * cst[r] + iv * gv;
        hv[r] = ov * thf(cst[r]);
    }
    unsigned d0, d1;
    asm("v_cvt_pkrtz_f16_f32 %0, %1, %2" : "=v"(d0) : "v"(hv[0]), "v"(hv[1]));
    asm("v_cvt_pkrtz_f16_f32 %0, %1, %2" : "=v"(d1) : "v"(hv[2]), "v"(hv[3]));
    *(uint2*)dst = make_uint2(d0, d1);
}

__global__ __launch_bounds__(NTH, 4)
void weather_lstm_mfma(const float* __restrict__ x,
                       const float* __restrict__ w_ih0, const float* __restrict__ w_hh0,
                       const float* __restrict__ b_ih0, const float* __restrict__ b_hh0,
                       const float* __restrict__ w_ih1, const float* __restrict__ w_hh1,
                       const float* __restrict__ b_ih1, const float* __restrict__ b_hh1,
                       const float* __restrict__ fc_w, const float* __restrict__ fc_b,
                       float* __restrict__ out)
{
    __shared__ f16x8 xs[2][CH][NS];                           // 8 KB
    __shared__ __align__(16) _Float16 h1[2][NS][72];          // 9.2 KB (144B rows)
    __shared__ __align__(16) _Float16 h2[2][NS][72];          // 9.2 KB
    // raw gate exchange: [gate 0..3][st][sample-in-tile][unit 0..63 +pad4]
    // col-stride 68 words -> bank 4*(col+kg) pattern = 2-way (free); 16B aligned
    __shared__ __align__(16) float gb0[4][2][16][68];         // 34.8 KB (layer 0)
    __shared__ __align__(16) float gb1[4][2][16][68];         // 34.8 KB (layer 1)

    const int tid  = threadIdx.x;
    const int wv   = tid >> 6;        // 0..15
    const int eng  = wv >> 3;         // 0 = layer0 engine, 1 = layer1 engine
    const int gh   = (wv >> 2) & 1;   // gate-pair: tiles {2gh, 2gh+1}
    const int ug   = wv & 3;          // unit group (units 16ug..16ug+15)
    const int lane = tid & 63;
    const int col  = lane & 15;       // sample within tile / weight row within tile
    const int kg   = lane >> 4;       // k-group
    const int s0   = blockIdx.x * NS;
    const int ubx  = 16 * ug + 4 * kg;   // unit base of this lane's C-frag / cells

    // ---------------- init: zero h (both parities), stage x chunk 0 ----------------
    for (int i = tid; i < 2 * NS * 72; i += NTH) {
        ((short*)h1)[i] = 0; ((short*)h2)[i] = 0;
    }
    if (tid < 256) {
        const int tloc = tid >> 5, ss = tid & 31;
        const float* px = x + ((size_t)(s0 + ss) * TT + tloc) * DD;
        f32x4 a, b;
        a[0] = px[0]; a[1] = px[1]; a[2] = px[2]; a[3] = px[3];
        b[0] = px[4]; b[1] = px[5]; b[2] = px[6]; b[3] = 1.0f;   // bias slot
        xs[0][tloc][ss] = pack8(a, b);
    }
    __syncthreads();

    const f16x8 z8 = {0, 0, 0, 0, 0, 0, 0, 0};

    if (eng == 0) {
        // ==================== LAYER-0 ENGINE (waves 0-7) ====================
        // tiles lt=0,1 -> gate rows 64*(2gh+lt) + 16*ug + col
        f16x8 W0h[2][2], W0l[2][2];   // w_hh0 (K=64) [lt][kf]
        f16x8 WXh[2],    WXl[2];      // w_ih0 + bias0 in k-slot 7
#pragma unroll
        for (int lt = 0; lt < 2; ++lt) {
            const int row = 64 * (2 * gh + lt) + 16 * ug + col;
#pragma unroll
            for (int kf = 0; kf < 2; ++kf) {
                const float* p = w_hh0 + (size_t)row * HH + 32 * kf + 8 * kg;
                wsplit8(*(const f32x4*)p, *(const f32x4*)(p + 4), W0h[lt][kf], W0l[lt][kf]);
            }
            f32x4 a = {0, 0, 0, 0}, b = {0, 0, 0, 0};
            if (kg == 0) {
                const float* p = w_ih0 + (size_t)row * DD;
                a[0] = p[0]; a[1] = p[1]; a[2] = p[2]; a[3] = p[3];
                b[0] = p[4]; b[1] = p[5]; b[2] = p[6];
                b[3] = b_ih0[row] + b_hh0[row];     // bias0 rides k-slot 7
            }
            wsplit8(a, b, WXh[lt], WXl[lt]);
        }
        f32x4 c1 = {0, 0, 0, 0};      // cells: units ubx..+3, sample 16*gh+col

#pragma unroll 1
        for (int k = 0; k <= TT + 1; ++k) {
            // ---------- Segment A: L0 MFMA for step k -> gb0 ----------
            if (k < TT) {
                if (tid < 256 && (k & 7) == 0 && k + CH < TT) {   // refill next x chunk
                    const int tloc = tid >> 5, ss = tid & 31;
                    const int tg = k + CH + tloc;
                    const float* px = x + ((size_t)(s0 + ss) * TT + tg) * DD;
                    f32x4 a, b;
                    a[0] = px[0]; a[1] = px[1]; a[2] = px[2]; a[3] = px[3];
                    b[0] = px[4]; b[1] = px[5]; b[2] = px[6]; b[3] = 1.0f;
                    const int nb = ((k >> 3) & 1) ^ 1;
                    xs[nb][tloc][ss] = pack8(a, b);
                }
                const int cb = (k >> 3) & 1, tt = k & 7;
                const int rp = (k - 1) & 1;             // h1(k-1) parity

                f32x4 acc[2][2];                        // [st][lt]
#pragma unroll
                for (int st = 0; st < 2; ++st)
#pragma unroll
                    for (int lt = 0; lt < 2; ++lt) acc[st][lt] = (f32x4){0, 0, 0, 0};

                __builtin_amdgcn_s_setprio(1);
#pragma unroll
                for (int st = 0; st < 2; ++st) {
                    f16x8 ax = z8;
                    if (kg == 0) ax = xs[cb][tt][16 * st + col];
                    TERM2(acc[st][0], WXh[0], WXl[0], ax)
                    TERM2(acc[st][1], WXh[1], WXl[1], ax)
#pragma unroll
                    for (int kf = 0; kf < 2; ++kf) {
                        const f16x8 dh = *(const f16x8*)&h1[rp][16 * st + col][32 * kf + 8 * kg];
                        TERM2(acc[st][0], W0h[0][kf], W0l[0][kf], dh)
                        TERM2(acc[st][1], W0h[1][kf], W0l[1][kf], dh)
                    }
                }
                __builtin_amdgcn_s_setprio(0);
#pragma unroll
                for (int st = 0; st < 2; ++st)
#pragma unroll
                    for (int lt = 0; lt < 2; ++lt)
                        *(f32x4*)&gb0[2 * gh + lt][st][col][ubx] = acc[st][lt];
            }
            __syncthreads();   // B1
            // ---------- Segment B: L0 cell update step k (reads gb0) ----------
            if (k < TT) {
                const int wp = k & 1;
                const f32x4 gi = *(const f32x4*)&gb0[0][gh][col][ubx];
                const f32x4 gf = *(const f32x4*)&gb0[1][gh][col][ubx];
                const f32x4 gg = *(const f32x4*)&gb0[2][gh][col][ubx];
                const f32x4 go = *(const f32x4*)&gb0[3][gh][col][ubx];
                cell_update(gi, gf, gg, go, c1, &h1[wp][16 * gh + col][ubx]);
            }
            __syncthreads();   // B2
        }
    } else {
        // ==================== LAYER-1 ENGINE (waves 8-15) ====================
        f16x8 W1h[2][4], W1l[2][4];   // [lt][kf]: kf 0..1 h1-input, kf 2..3 h2-input
        f32x4 bias1[2];
#pragma unroll
        for (int lt = 0; lt < 2; ++lt) {
            const int row = 64 * (2 * gh + lt) + 16 * ug + col;
            const int rr  = 64 * (2 * gh + lt) + 16 * ug + 4 * kg;
            bias1[lt] = *(const f32x4*)(b_ih1 + rr) + *(const f32x4*)(b_hh1 + rr);
#pragma unroll
            for (int kf = 0; kf < 4; ++kf) {
                const float* base = (kf < 2) ? (w_ih1 + (size_t)row * HH + 32 * kf)
                                             : (w_hh1 + (size_t)row * HH + 32 * (kf - 2));
                const float* p = base + 8 * kg;
                wsplit8(*(const f32x4*)p, *(const f32x4*)(p + 4), W1h[lt][kf], W1l[lt][kf]);
            }
        }
        f32x4 c2 = {0, 0, 0, 0};      // cells: units ubx..+3, sample 16*gh+col

#pragma unroll 1
        for (int k = 0; k <= TT + 1; ++k) {
            // ---------- Segment A: L1 cell update step k-2 (reads gb1) ----------
            if (k >= 2) {
                const int wp = k & 1;                   // (k-2)&1
                const f32x4 gi = *(const f32x4*)&gb1[0][gh][col][ubx];
                const f32x4 gf = *(const f32x4*)&gb1[1][gh][col][ubx];
                const f32x4 gg = *(const f32x4*)&gb1[2][gh][col][ubx];
                const f32x4 go = *(const f32x4*)&gb1[3][gh][col][ubx];
                cell_update(gi, gf, gg, go, c2, &h2[wp][16 * gh + col][ubx]);
            }
            __syncthreads();   // B1
            // ---------- Segment B: L1 MFMA for step k-1 -> gb1 ----------
            if (k >= 1 && k <= TT) {
                const int rp1 = (k - 1) & 1;            // h1(k-1) parity
                const int rp2 = k & 1;                  // h2(k-2) parity

                f32x4 acc[2][2];                        // [st][lt]
#pragma unroll
                for (int st = 0; st < 2; ++st)
#pragma unroll
                    for (int lt = 0; lt < 2; ++lt) acc[st][lt] = bias1[lt];

                __builtin_amdgcn_s_setprio(1);
#pragma unroll
                for (int st = 0; st < 2; ++st) {
#pragma unroll
                    for (int kf = 0; kf < 2; ++kf) {    // h1(k-1) input
                        const f16x8 dh = *(const f16x8*)&h1[rp1][16 * st + col][32 * kf + 8 * kg];
                        TERM2(acc[st][0], W1h[0][kf], W1l[0][kf], dh)
                        TERM2(acc[st][1], W1h[1][kf], W1l[1][kf], dh)
                    }
#pragma unroll
                    for (int kf = 0; kf < 2; ++kf) {    // h2(k-2) input
                        const f16x8 eh = *(const f16x8*)&h2[rp2][16 * st + col][32 * kf + 8 * kg];
                        TERM2(acc[st][0], W1h[0][kf + 2], W1l[0][kf + 2], eh)
                        TERM2(acc[st][1], W1h[1][kf + 2], W1l[1][kf + 2], eh)
                    }
                }
                __builtin_amdgcn_s_setprio(0);
#pragma unroll
                for (int st = 0; st < 2; ++st)
#pragma unroll
                    for (int lt = 0; lt < 2; ++lt)
                        *(f32x4*)&gb1[2 * gh + lt][st][col][ubx] = acc[st][lt];
            }
            __syncthreads();   // B2
        }
    }

    // ---------------- FC head on final h2 = h2(TT-1), parity (TT+1)&1 = 1 ----------------
    if (tid < NS * 4) {
        const int s = tid >> 2, k = tid & 3;
        float a = fc_b[k];
#pragma unroll
        for (int j = 0; j < HH; ++j)
            a = fmaf((float)h2[1][s][j], fc_w[k * HH + j], a);
        out[(size_t)(s0 + s) * 4 + k] = a;
    }
}

extern "C" void kernel_launch(void* const* d_in, const int* in_sizes, int n_in,
                              void* d_out, int out_size, void* d_ws, size_t ws_size,
                              hipStream_t stream) {
    const float* x     = (const float*)d_in[0];
    const float* w_ih0 = (const float*)d_in[1];
    const float* w_hh0 = (const float*)d_in[2];
    const float* b_ih0 = (const float*)d_in[3];
    const float* b_hh0 = (const float*)d_in[4];
    const float* w_ih1 = (const float*)d_in[5];
    const float* w_hh1 = (const float*)d_in[6];
    const float* b_ih1 = (const float*)d_in[7];
    const float* b_hh1 = (const float*)d_in[8];
    const float* fc_w  = (const float*)d_in[9];
    const float* fc_b  = (const float*)d_in[10];
    float* out = (float*)d_out;

    dim3 grid(BB / NS), block(NTH);
    weather_lstm_mfma<<<grid, block, 0, stream>>>(
        x, w_ih0, w_hh0, b_ih0, b_hh0,
        w_ih1, w_hh1, b_ih1, b_hh1, fc_w, fc_b, out);
}